// Round 8
// baseline (102.251 us; speedup 1.0000x reference)
//
#include <hip/hip_runtime.h>
#include <hip/hip_bf16.h>
#include <math.h>

#define B_ 8
#define S_ 4096
#define C_ 64
#define EPSV 1e-5f

using floatx4 = __attribute__((ext_vector_type(4))) float;
using bf16x8  = __attribute__((ext_vector_type(8))) short;
using bf16x4  = __attribute__((ext_vector_type(4))) short;

typedef __attribute__((address_space(3))) unsigned int       as3_u32;
typedef __attribute__((address_space(1))) const unsigned int as1_u32;

__device__ __forceinline__ short f2bf(float f) {
    unsigned u = __builtin_bit_cast(unsigned, f);
    u = u + 0x7fffu + ((u >> 16) & 1u);   // RNE
    return (short)(u >> 16);
}

__device__ __forceinline__ unsigned cvt_pk_bf16(float lo, float hi) {
    unsigned r;
    asm volatile("v_cvt_pk_bf16_f32 %0, %1, %2" : "=v"(r) : "v"(lo), "v"(hi));
    return r;
}

// PV MFMA: 16x16x16 bf16 (K=16) — B-fragment layout (col=c, k=4g+j) matches
// the swapped-QK^T accumulator layout directly -> no cross-lane redistribution.
__device__ __forceinline__ floatx4 mfma_16x16x16_bf16(bf16x4 a, bf16x4 b, floatx4 c) {
#if __has_builtin(__builtin_amdgcn_mfma_f32_16x16x16bf16_1k)
    return __builtin_amdgcn_mfma_f32_16x16x16bf16_1k(a, b, c, 0, 0, 0);
#else
    asm("v_mfma_f32_16x16x16_bf16 %0, %1, %2, %0" : "+v"(c) : "v"(a), "v"(b));
    return c;
#endif
}

// B-fragment from a row-major fp32 64x64 weight matrix.
__device__ __forceinline__ bf16x8 ld_w_frag(const float* __restrict__ W, int n, int kk, int g, int c) {
    const float* p = W + (16 * n + c) * C_ + 32 * kk + 8 * g;
    bf16x8 r;
#pragma unroll
    for (int j = 0; j < 8; ++j) r[j] = f2bf(p[j]);
    return r;
}

// ---------------- kernel 1a: per-chunk partial sums ----------------
__global__ __launch_bounds__(256) void stats1_kernel(const float* __restrict__ x,
                                                     float* __restrict__ partial) {
    int b = blockIdx.x >> 5, chunk = blockIdx.x & 31;
    const float4* xb = (const float4*)x + (size_t)b * 65536 + chunk * 2048;
    float s = 0.f, ss = 0.f;
#pragma unroll
    for (int i = 0; i < 8; ++i) {
        float4 v = xb[threadIdx.x + i * 256];
        s  += v.x + v.y + v.z + v.w;
        ss += v.x * v.x + v.y * v.y + v.z * v.z + v.w * v.w;
    }
    for (int off = 32; off > 0; off >>= 1) {
        s  += __shfl_down(s, off);
        ss += __shfl_down(ss, off);
    }
    __shared__ float sm[4], ssm[4];
    int wid = threadIdx.x >> 6, lane = threadIdx.x & 63;
    if (lane == 0) { sm[wid] = s; ssm[wid] = ss; }
    __syncthreads();
    if (threadIdx.x == 0) {
        partial[blockIdx.x * 2]     = sm[0] + sm[1] + sm[2] + sm[3];
        partial[blockIdx.x * 2 + 1] = ssm[0] + ssm[1] + ssm[2] + ssm[3];
    }
}

// ---------------- kernel 1b: finalize mean / rsqrt(var) ----------------
__global__ __launch_bounds__(512) void stats2_kernel(const float* __restrict__ partial,
                                                     float* __restrict__ stats) {
    int w = threadIdx.x >> 6, lane = threadIdx.x & 63;  // wave w = batch w
    float s = 0.f, ss = 0.f;
    if (lane < 32) {
        s  = partial[(w * 32 + lane) * 2];
        ss = partial[(w * 32 + lane) * 2 + 1];
    }
    for (int off = 16; off > 0; off >>= 1) {
        s  += __shfl_down(s, off);
        ss += __shfl_down(ss, off);
    }
    if (lane == 0) {
        const float invN = 1.0f / (float)(S_ * C_);
        float mu  = s * invN;
        float var = ss * invN - mu * mu;
        stats[w * 2]     = mu;
        stats[w * 2 + 1] = rsqrtf(var + EPSV);
    }
}

// ---------------- kernel 2: normalize + Q/K/V^T projections ----------------
// K and V^T are written as per-64-kv TILE IMAGES (8192 B each), XOR-swizzled
// exactly as the flash kernel's LDS wants them (both-sides rule).
//   K tile:  [64 kv-rows][64 ch] bf16, byte = (r*128 + ch*2) ^ ((r&7)<<4)
//   V tile:  [64 ch-rows][64 kv] bf16, byte = (ch*128 + u*2) ^ ((ch&7)<<4)
__global__ __launch_bounds__(256) void proj_kernel(
    const float* __restrict__ x,
    const float* __restrict__ Wq, const float* __restrict__ bq,
    const float* __restrict__ Wk, const float* __restrict__ bk,
    const float* __restrict__ Wv, const float* __restrict__ bv,
    const float* __restrict__ stats,
    short* __restrict__ qo, char* __restrict__ kws, char* __restrict__ vws) {
    __shared__ char hbuf[64 * 128];  // [64 rows][64 bf16], XOR-swizzled

    int b  = blockIdx.x >> 6;
    int t_ = blockIdx.x & 63;        // 64-row tile index within batch
    int s0 = t_ * 64;
    float mu = stats[b * 2], rs = stats[b * 2 + 1];
    const float* xt = x + ((size_t)b * S_ + s0) * C_;
    int t = threadIdx.x;

#pragma unroll
    for (int i = 0; i < 4; ++i) {
        int fi  = t + 256 * i;       // float4 index within 64x64 tile
        int row = fi >> 4;
        int c4  = fi & 15;
        float4 v = *(const float4*)(xt + row * C_ + c4 * 4);
        unsigned lo = (unsigned)(unsigned short)f2bf((v.x - mu) * rs) |
                      ((unsigned)(unsigned short)f2bf((v.y - mu) * rs) << 16);
        unsigned hi = (unsigned)(unsigned short)f2bf((v.z - mu) * rs) |
                      ((unsigned)(unsigned short)f2bf((v.w - mu) * rs) << 16);
        int off = row * 128 + c4 * 8;
        off ^= (row & 7) << 4;
        *(uint2*)(hbuf + off) = make_uint2(lo, hi);
    }
    __syncthreads();

    int lane = t & 63, w = t >> 6;
    int g = lane >> 4, c = lane & 15;

    auto ld_h = [&](int row, int kcol) -> bf16x8 {
        int off = row * 128 + kcol * 2;
        off ^= (row & 7) << 4;
        return *(const bf16x8*)(hbuf + off);
    };

    size_t tilebase = ((size_t)b * 64 + t_) * 8192;

    // ---- Q and K: D = h @ W^T.  A = h rows 16w..16w+15 ----
    bf16x8 ha[2];
    ha[0] = ld_h(16 * w + c, 8 * g);
    ha[1] = ld_h(16 * w + c, 32 + 8 * g);

    const float QSC = 0.125f * 1.44269504088896340736f;  // C^-0.5 * log2(e)

#pragma unroll
    for (int n = 0; n < 4; ++n) {
        floatx4 aq = {0.f, 0.f, 0.f, 0.f}, ak = {0.f, 0.f, 0.f, 0.f};
#pragma unroll
        for (int kk = 0; kk < 2; ++kk) {
            bf16x8 wq = ld_w_frag(Wq, n, kk, g, c);
            bf16x8 wk = ld_w_frag(Wk, n, kk, g, c);
            aq = __builtin_amdgcn_mfma_f32_16x16x32_bf16(ha[kk], wq, aq, 0, 0, 0);
            ak = __builtin_amdgcn_mfma_f32_16x16x32_bf16(ha[kk], wk, ak, 0, 0, 0);
        }
        float bqv = bq[16 * n + c], bkv = bk[16 * n + c];
#pragma unroll
        for (int r = 0; r < 4; ++r) {
            int rr = 16 * w + 4 * g + r;          // kv row within tile
            qo[((size_t)b * S_ + s0 + rr) * C_ + 16 * n + c] = f2bf((aq[r] + bqv) * QSC);
            int koff = (rr * 128 + (16 * n + c) * 2) ^ ((rr & 7) << 4);
            *(short*)(kws + tilebase + koff) = f2bf(ak[r] + bkv);
        }
    }

    // ---- V^T = Wv @ h^T (direct transposed, swizzled tile image) ----
    bf16x8 wv[2];
    wv[0] = ld_w_frag(Wv, w, 0, g, c);
    wv[1] = ld_w_frag(Wv, w, 1, g, c);
    float bvr[4];
#pragma unroll
    for (int r = 0; r < 4; ++r) bvr[r] = bv[16 * w + 4 * g + r];

#pragma unroll
    for (int n = 0; n < 4; ++n) {
        floatx4 av = {0.f, 0.f, 0.f, 0.f};
#pragma unroll
        for (int kk = 0; kk < 2; ++kk) {
            bf16x8 hb = ld_h(16 * n + c, 32 * kk + 8 * g);
            av = __builtin_amdgcn_mfma_f32_16x16x32_bf16(wv[kk], hb, av, 0, 0, 0);
        }
#pragma unroll
        for (int r = 0; r < 4; ++r) {
            int rr = 16 * w + 4 * g + r;          // channel row
            int u  = 16 * n + c;                  // kv col within tile
            int voff = (rr * 128 + u * 2) ^ ((rr & 7) << 4);
            *(short*)(vws + tilebase + voff) = f2bf(av[r] + bvr[r]);
        }
    }
}

// ---------------- kernel 3: wave-sliced flash attention + Wo + residual ----------------
// Block = 64 q rows. Wave w owns kv rows 16w..16w+15 of EVERY staged tile and
// computes a partial O[64ch][64q] (64 VGPR) with its own per-q online (m,l).
// LDS reads per wave per tile: 2KB K-slice + 2KB V-slice (4x less than R7).
// End: cross-wave LSE combine through LDS, then Wo projection + residual.
__global__ __launch_bounds__(256) void flash_kernel(
    const short* __restrict__ qm, const char* __restrict__ kws, const char* __restrict__ vws,
    const float* __restrict__ Wo, const float* __restrict__ bo,
    const float* __restrict__ x, float* __restrict__ out) {
    __shared__ char kb[2][8192];
    __shared__ char vb[2][8192];
    __shared__ float buf[64][68];      // combined O (q rows, ch cols)
    __shared__ float mlb[4][2][64];    // per-wave m,l per q
    __shared__ float Lq[64];           // final denominators

    int bid = blockIdx.x;
    int logical = (bid & 7) * 64 + (bid >> 3);  // XCD swizzle: batch b -> XCD b
    int b = logical >> 6;
    int q0 = (logical & 63) * 64;
    int t = threadIdx.x;
    int lane = t & 63, w = t >> 6;
    int g = lane >> 4, c = lane & 15;

    const char* kbase = kws + (size_t)b * 64 * 8192;
    const char* vbase = vws + (size_t)b * 64 * 8192;
    const short* qp = qm + (size_t)b * S_ * C_;

    // Q^T B-fragments for ALL 64 q rows (4 subtiles), held in regs.
    bf16x8 bqf[4][2];
#pragma unroll
    for (int qi = 0; qi < 4; ++qi) {
        bqf[qi][0] = *(const bf16x8*)(qp + (q0 + 16 * qi + c) * C_ + 8 * g);
        bqf[qi][1] = *(const bf16x8*)(qp + (q0 + 16 * qi + c) * C_ + 32 + 8 * g);
    }

    floatx4 oacc[4][4];                // [mi(ch)][qi]
#pragma unroll
    for (int mi = 0; mi < 4; ++mi)
#pragma unroll
        for (int qi = 0; qi < 4; ++qi) oacc[mi][qi] = (floatx4){0.f, 0.f, 0.f, 0.f};
    float m[4], l[4];
#pragma unroll
    for (int qi = 0; qi < 4; ++qi) { m[qi] = -__builtin_inff(); l[qi] = 0.f; }

    const int xmask = (c & 7) << 4;   // per-lane row-swizzle mask (bits 4-6)

    auto STAGE = [&](int bi, int tt) {
        const char* gk = kbase + (size_t)tt * 8192 + w * 2048 + lane * 16;
        const char* gv = vbase + (size_t)tt * 8192 + w * 2048 + lane * 16;
        char* lk = &kb[bi][w * 2048];
        char* lv = &vb[bi][w * 2048];
        __builtin_amdgcn_global_load_lds((as1_u32*)gk,          (as3_u32*)lk,          16, 0, 0);
        __builtin_amdgcn_global_load_lds((as1_u32*)(gk + 1024), (as3_u32*)(lk + 1024), 16, 0, 0);
        __builtin_amdgcn_global_load_lds((as1_u32*)gv,          (as3_u32*)lv,          16, 0, 0);
        __builtin_amdgcn_global_load_lds((as1_u32*)(gv + 1024), (as3_u32*)(lv + 1024), 16, 0, 0);
    };

    auto COMPUTE = [&](const char* kbuf, const char* vbuf) {
        // K slice (rows 16w..16w+15): 2 x ds_read_b128
        bf16x8 ak0 = *(const bf16x8*)(kbuf + w * 2048 + c * 128 + ((16 * g) ^ xmask));
        bf16x8 ak1 = *(const bf16x8*)(kbuf + w * 2048 + c * 128 + ((64 + 16 * g) ^ xmask));
        // ---- S^T slice (16 kv x 64 q) ----
        floatx4 st[4];
        __builtin_amdgcn_s_setprio(1);
#pragma unroll
        for (int qi = 0; qi < 4; ++qi) {
            st[qi] = (floatx4){0.f, 0.f, 0.f, 0.f};
            st[qi] = __builtin_amdgcn_mfma_f32_16x16x32_bf16(ak0, bqf[qi][0], st[qi], 0, 0, 0);
            st[qi] = __builtin_amdgcn_mfma_f32_16x16x32_bf16(ak1, bqf[qi][1], st[qi], 0, 0, 0);
        }
        __builtin_amdgcn_s_setprio(0);
        // ---- online softmax per q-subtile (q = 16qi + c; log2-domain) ----
        bf16x4 pb[4];
#pragma unroll
        for (int qi = 0; qi < 4; ++qi) {
            float mt = fmaxf(fmaxf(st[qi][0], st[qi][1]), fmaxf(st[qi][2], st[qi][3]));
            mt = fmaxf(mt, __shfl_xor(mt, 16));
            mt = fmaxf(mt, __shfl_xor(mt, 32));
            // defer-max (T13): skip rescale unless max grew by > 8
            if (!__all(mt - m[qi] <= 8.0f)) {
                float mnew  = fmaxf(m[qi], mt);
                float alpha = __builtin_amdgcn_exp2f(m[qi] - mnew);
                l[qi] *= alpha;
                m[qi] = mnew;
#pragma unroll
                for (int mi = 0; mi < 4; ++mi) oacc[mi][qi] *= alpha;
            }
            float e0 = __builtin_amdgcn_exp2f(st[qi][0] - m[qi]);
            float e1 = __builtin_amdgcn_exp2f(st[qi][1] - m[qi]);
            float e2 = __builtin_amdgcn_exp2f(st[qi][2] - m[qi]);
            float e3 = __builtin_amdgcn_exp2f(st[qi][3] - m[qi]);
            l[qi] += (e0 + e1) + (e2 + e3);
            uint2 u = make_uint2(cvt_pk_bf16(e0, e1), cvt_pk_bf16(e2, e3));
            pb[qi] = __builtin_bit_cast(bf16x4, u);
        }
        // V slice (kv cols 16w..16w+15): 4 x ds_read_b64
        bf16x4 av[4];
#pragma unroll
        for (int mi = 0; mi < 4; ++mi)
            av[mi] = *(const bf16x4*)(vbuf + mi * 2048 + c * 128 + ((32 * w + 8 * g) ^ xmask));
        // ---- O^T partial += V^T @ P^T (16 independent MFMA16) ----
        __builtin_amdgcn_s_setprio(1);
#pragma unroll
        for (int qi = 0; qi < 4; ++qi)
#pragma unroll
            for (int mi = 0; mi < 4; ++mi)
                oacc[mi][qi] = mfma_16x16x16_bf16(av[mi], pb[qi], oacc[mi][qi]);
        __builtin_amdgcn_s_setprio(0);
    };

    STAGE(0, 0);
    __syncthreads();
    for (int tt = 0; tt < 64; tt += 2) {
        STAGE(1, tt + 1);
        COMPUTE(kb[0], vb[0]);
        __syncthreads();
        if (tt + 2 < 64) STAGE(0, tt + 2);
        COMPUTE(kb[1], vb[1]);
        __syncthreads();
    }

    // ---- cross-wave combine: publish (m, l) per q ----
#pragma unroll
    for (int qi = 0; qi < 4; ++qi) {
        l[qi] += __shfl_xor(l[qi], 16);
        l[qi] += __shfl_xor(l[qi], 32);
    }
    if (lane < 16) {
#pragma unroll
        for (int qi = 0; qi < 4; ++qi) {
            mlb[w][0][16 * qi + lane] = m[qi];
            mlb[w][1][16 * qi + lane] = l[qi];
        }
    }
    __syncthreads();

    float sc[4], L[4];
#pragma unroll
    for (int qi = 0; qi < 4; ++qi) {
        int q = 16 * qi + c;
        float m0 = mlb[0][0][q], m1 = mlb[1][0][q], m2 = mlb[2][0][q], m3 = mlb[3][0][q];
        float M = fmaxf(fmaxf(m0, m1), fmaxf(m2, m3));
        L[qi] = mlb[0][1][q] * __builtin_amdgcn_exp2f(m0 - M) +
                mlb[1][1][q] * __builtin_amdgcn_exp2f(m1 - M) +
                mlb[2][1][q] * __builtin_amdgcn_exp2f(m2 - M) +
                mlb[3][1][q] * __builtin_amdgcn_exp2f(m3 - M);
        sc[qi] = __builtin_amdgcn_exp2f(m[qi] - M);
    }
    if (w == 0 && lane < 16) {
#pragma unroll
        for (int qi = 0; qi < 4; ++qi) Lq[16 * qi + lane] = L[qi];
    }

    // ---- serial 4-phase scaled add into buf[q][ch] ----
#pragma unroll
    for (int ph = 0; ph < 4; ++ph) {
        if (w == ph) {
#pragma unroll
            for (int mi = 0; mi < 4; ++mi)
#pragma unroll
                for (int qi = 0; qi < 4; ++qi)
#pragma unroll
                    for (int r = 0; r < 4; ++r) {
                        float v = oacc[mi][qi][r] * sc[qi];
                        float* p = &buf[16 * qi + c][16 * mi + 4 * g + r];
                        if (ph == 0) *p = v; else *p += v;
                    }
        }
        __syncthreads();
    }

    // ---- epilogue: wave w handles q rows q0+16w..+15; out = o @ Wo^T + bo + x ----
    int qw = q0 + 16 * w;
    float invL = 1.0f / Lq[16 * w + c];
    bf16x8 ao[2];
#pragma unroll
    for (int kk = 0; kk < 2; ++kk) {
        bf16x8 tr;
#pragma unroll
        for (int j = 0; j < 8; ++j) tr[j] = f2bf(buf[16 * w + c][32 * kk + 8 * g + j] * invL);
        ao[kk] = tr;
    }
#pragma unroll
    for (int n = 0; n < 4; ++n) {
        floatx4 a = {0.f, 0.f, 0.f, 0.f};
#pragma unroll
        for (int kk = 0; kk < 2; ++kk) {
            bf16x8 bw = ld_w_frag(Wo, n, kk, g, c);
            a = __builtin_amdgcn_mfma_f32_16x16x32_bf16(ao[kk], bw, a, 0, 0, 0);
        }
        float bov = bo[16 * n + c];
#pragma unroll
        for (int r = 0; r < 4; ++r) {
            int srow = qw + 4 * g + r;
            size_t idx = ((size_t)b * S_ + srow) * C_ + 16 * n + c;
            out[idx] = x[idx] + bov + a[r];
        }
    }
}

extern "C" void kernel_launch(void* const* d_in, const int* in_sizes, int n_in,
                              void* d_out, int out_size, void* d_ws, size_t ws_size,
                              hipStream_t stream) {
    const float* x  = (const float*)d_in[0];
    // d_in[1] = temb (unused by reference)
    const float* Wq = (const float*)d_in[2];
    const float* bq = (const float*)d_in[3];
    const float* Wk = (const float*)d_in[4];
    const float* bk = (const float*)d_in[5];
    const float* Wv = (const float*)d_in[6];
    const float* bv = (const float*)d_in[7];
    const float* Wo = (const float*)d_in[8];
    const float* bo = (const float*)d_in[9];
    float* out = (float*)d_out;

    char* ws = (char*)d_ws;
    float* partial = (float*)ws;                    // 512 floats
    float* stats   = (float*)(ws + 2048);           // 16 floats
    short* q  = (short*)(ws + 4096);                // [B][S][C] bf16 (4 MB)
    char*  kt = (char*)(q + (size_t)B_ * S_ * C_);  // [B][64 tiles][8192 B] swizzled K
    char*  vt = kt + (size_t)B_ * 64 * 8192;        // [B][64 tiles][8192 B] swizzled V^T

    stats1_kernel<<<256, 256, 0, stream>>>(x, partial);
    stats2_kernel<<<1, 512, 0, stream>>>(partial, stats);
    proj_kernel<<<B_ * (S_ / 64), 256, 0, stream>>>(x, Wq, bq, Wk, bk, Wv, bv, stats, q, kt, vt);
    flash_kernel<<<B_ * (S_ / 64), 256, 0, stream>>>(q, kt, vt, Wo, bo, x, out);
}